// Round 1
// baseline (5704.592 us; speedup 1.0000x reference)
//
#include <hip/hip_runtime.h>
#include <math.h>

#define N_NODES 50000
#define E_EDGES 1600000
#define EP_EDGES (E_EDGES + N_NODES)
#define IN_F 512
#define HID 256
#define HEADS 8
#define OUTF 128

static __device__ __forceinline__ float eluf(float x) {
  return x > 0.f ? x : expm1f(x);
}

// ---------------- CSR build ----------------

// Detect whether edge_index is stored as int64 (odd 32-bit words all zero)
// or int32. flag=1 -> int64 layout (stride 2), flag=0 -> int32.
__global__ void k_detect(const int* __restrict__ ei, int* __restrict__ flag) {
  __shared__ int nz;
  if (threadIdx.x == 0) nz = 0;
  __syncthreads();
  for (int i = threadIdx.x; i < 4096; i += blockDim.x)
    if (ei[2 * i + 1] != 0) nz = 1;   // benign race
  __syncthreads();
  if (threadIdx.x == 0) *flag = (nz ? 0 : 1);
}

__global__ void k_init_deg(int* __restrict__ deg, int n) {
  int i = blockIdx.x * 256 + threadIdx.x;
  if (i < n) deg[i] = 1;   // self loop
}

__global__ void k_count(const int* __restrict__ ei, const int* __restrict__ flag,
                        int* __restrict__ deg, int E) {
  int e = blockIdx.x * 256 + threadIdx.x;
  if (e >= E) return;
  int f = *flag;
  int idx = E + e;                       // row 1 = dst
  int dst = ei[f ? 2 * idx : idx];
  atomicAdd(&deg[dst], 1);
}

__global__ __launch_bounds__(1024) void k_scan(const int* __restrict__ deg,
                                               int* __restrict__ rp, int n) {
  __shared__ int sd[1024];
  __shared__ int s_run;
  int tid = threadIdx.x;
  if (tid == 0) s_run = 0;
  __syncthreads();
  for (int base = 0; base < n; base += 1024) {
    int i = base + tid;
    int v = (i < n) ? deg[i] : 0;
    sd[tid] = v;
    __syncthreads();
    for (int off = 1; off < 1024; off <<= 1) {
      int t = (tid >= off) ? sd[tid - off] : 0;
      __syncthreads();
      sd[tid] += t;
      __syncthreads();
    }
    int run = s_run;
    if (i < n) rp[i + 1] = run + sd[tid];
    __syncthreads();
    if (tid == 1023) s_run = run + sd[1023];
    __syncthreads();
  }
  if (tid == 0) rp[0] = 0;
}

__global__ void k_fill_self(const int* __restrict__ rp, int* __restrict__ wp,
                            int* __restrict__ col, int n) {
  int i = blockIdx.x * 256 + threadIdx.x;
  if (i < n) { int p = rp[i]; col[p] = i; wp[i] = p + 1; }
}

__global__ void k_fill_edges(const int* __restrict__ ei, const int* __restrict__ flag,
                             int* __restrict__ wp, int* __restrict__ col, int E) {
  int e = blockIdx.x * 256 + threadIdx.x;
  if (e >= E) return;
  int f = *flag;
  int src = ei[f ? 2 * e : e];
  int didx = E + e;
  int dst = ei[f ? 2 * didx : didx];
  int p = atomicAdd(&wp[dst], 1);
  col[p] = src;
}

// ---------------- fp32 GEMM: C[M,N] (+)= A[M,K] @ B[K,N] ----------------
// BM=64, BN=64, BK=32; 256 threads, 4x4 micro-tile per thread.
#define BM 64
#define BN 64
#define BK 32

__global__ __launch_bounds__(256) void gemm_f32(
    const float* __restrict__ A, int lda,
    const float* __restrict__ B, int ldb,
    float* __restrict__ C, int ldc,
    int M, int K, int accumulate) {
  __shared__ __align__(16) float As[BK][68];  // transposed A tile [k][row], pad 68
  __shared__ __align__(16) float Bs[BK][BN];
  int tid = threadIdx.x;
  int tx = tid & 15, ty = tid >> 4;
  int row0 = blockIdx.x * BM;
  int col0 = blockIdx.y * BN;
  float acc[4][4] = {};
  for (int k0 = 0; k0 < K; k0 += BK) {
    // A tile: 64 rows x 32 k = 512 float4 loads
#pragma unroll
    for (int t = tid; t < 512; t += 256) {
      int r = t >> 3, q = t & 7;
      int gr = row0 + r;
      float4 a = make_float4(0.f, 0.f, 0.f, 0.f);
      if (gr < M) a = *(const float4*)(A + (size_t)gr * lda + k0 + 4 * q);
      As[4 * q + 0][r] = a.x;
      As[4 * q + 1][r] = a.y;
      As[4 * q + 2][r] = a.z;
      As[4 * q + 3][r] = a.w;
    }
    // B tile: 32 k x 64 cols = 512 float4 loads
#pragma unroll
    for (int t = tid; t < 512; t += 256) {
      int kk = t >> 4, cq = t & 15;
      float4 b = *(const float4*)(B + (size_t)(k0 + kk) * ldb + col0 + 4 * cq);
      *(float4*)&Bs[kk][4 * cq] = b;
    }
    __syncthreads();
#pragma unroll 8
    for (int k = 0; k < BK; ++k) {
      float4 a = *(const float4*)&As[k][ty * 4];
      float4 b = *(const float4*)&Bs[k][tx * 4];
      acc[0][0] += a.x * b.x; acc[0][1] += a.x * b.y; acc[0][2] += a.x * b.z; acc[0][3] += a.x * b.w;
      acc[1][0] += a.y * b.x; acc[1][1] += a.y * b.y; acc[1][2] += a.y * b.z; acc[1][3] += a.y * b.w;
      acc[2][0] += a.z * b.x; acc[2][1] += a.z * b.y; acc[2][2] += a.z * b.z; acc[2][3] += a.z * b.w;
      acc[3][0] += a.w * b.x; acc[3][1] += a.w * b.y; acc[3][2] += a.w * b.z; acc[3][3] += a.w * b.w;
    }
    __syncthreads();
  }
#pragma unroll
  for (int i = 0; i < 4; ++i) {
    int gr = row0 + ty * 4 + i;
    if (gr < M) {
      float4* cp = (float4*)(C + (size_t)gr * ldc + col0 + tx * 4);
      float4 v = make_float4(acc[i][0], acc[i][1], acc[i][2], acc[i][3]);
      if (accumulate) {
        float4 o = *cp;
        v.x += o.x; v.y += o.y; v.z += o.z; v.w += o.w;
      }
      *cp = v;
    }
  }
}

// ---------------- attention dot products a_src/a_dst ----------------
template <int C>
__global__ __launch_bounds__(256) void att_dot(
    const float* __restrict__ h, const float* __restrict__ attS,
    const float* __restrict__ attD, float* __restrict__ aS,
    float* __restrict__ aD, int n) {
  int node = (blockIdx.x * 256 + threadIdx.x) >> 6;
  int lane = threadIdx.x & 63;
  if (node >= n) return;
  float s = 0.f, d = 0.f;
  if (C == 256) {
    float4 hv = *(const float4*)&h[(size_t)node * C + lane * 4];
    float4 sv = *(const float4*)&attS[lane * 4];
    float4 dv = *(const float4*)&attD[lane * 4];
    s = hv.x * sv.x + hv.y * sv.y + hv.z * sv.z + hv.w * sv.w;
    d = hv.x * dv.x + hv.y * dv.y + hv.z * dv.z + hv.w * dv.w;
  } else {
    float2 hv = *(const float2*)&h[(size_t)node * C + lane * 2];
    float2 sv = *(const float2*)&attS[lane * 2];
    float2 dv = *(const float2*)&attD[lane * 2];
    s = hv.x * sv.x + hv.y * sv.y;
    d = hv.x * dv.x + hv.y * dv.y;
  }
  for (int off = 32; off; off >>= 1) {
    s += __shfl_xor(s, off);
    d += __shfl_xor(d, off);
  }
  if (lane == 0) { aS[node] = s; aD[node] = d; }
}

// ---------------- layer-1 aggregation (C=256, one wave per dst node) ------
__global__ __launch_bounds__(256) void aggr_l1(
    const int* __restrict__ rp, const int* __restrict__ col,
    const float* __restrict__ aS, const float* __restrict__ aD,
    const float* __restrict__ h, const float* __restrict__ bias,
    float* __restrict__ out, int n) {
  int node = (blockIdx.x * 256 + threadIdx.x) >> 6;
  int lane = threadIdx.x & 63;
  if (node >= n) return;
  int s0 = rp[node], s1 = rp[node + 1];
  float ad = aD[node];
  float m = -3.0e38f;
  for (int i = s0 + lane; i < s1; i += 64) {
    float e = aS[col[i]] + ad;
    e = e >= 0.f ? e : 0.2f * e;
    m = fmaxf(m, e);
  }
  for (int off = 32; off; off >>= 1) m = fmaxf(m, __shfl_xor(m, off));
  float sum = 0.f;
  for (int i = s0 + lane; i < s1; i += 64) {
    float e = aS[col[i]] + ad;
    e = e >= 0.f ? e : 0.2f * e;
    sum += expf(e - m);
  }
  for (int off = 32; off; off >>= 1) sum += __shfl_xor(sum, off);
  float denom = sum + 1e-16f;
  float4 acc = make_float4(0.f, 0.f, 0.f, 0.f);
  for (int i = s0; i < s1; ++i) {
    int s = col[i];                     // wave-uniform
    float e = aS[s] + ad;
    e = e >= 0.f ? e : 0.2f * e;
    float a = expf(e - m) / denom;
    float4 hv = *(const float4*)&h[(size_t)s * HID + lane * 4];
    acc.x += a * hv.x; acc.y += a * hv.y; acc.z += a * hv.z; acc.w += a * hv.w;
  }
  float4 bb = *(const float4*)&bias[lane * 4];
  acc.x = eluf(acc.x + bb.x);
  acc.y = eluf(acc.y + bb.y);
  acc.z = eluf(acc.z + bb.z);
  acc.w = eluf(acc.w + bb.w);
  *(float4*)&out[(size_t)node * HID + lane * 4] = acc;
}

// ---------------- layer-2 aggregation (C=128) ----------------
__global__ __launch_bounds__(256) void aggr_l2(
    const int* __restrict__ rp, const int* __restrict__ col,
    const float* __restrict__ aS, const float* __restrict__ aD,
    const float* __restrict__ h, const float* __restrict__ bias,
    float* __restrict__ out, int n) {
  int node = (blockIdx.x * 256 + threadIdx.x) >> 6;
  int lane = threadIdx.x & 63;
  if (node >= n) return;
  int s0 = rp[node], s1 = rp[node + 1];
  float ad = aD[node];
  float m = -3.0e38f;
  for (int i = s0 + lane; i < s1; i += 64) {
    float e = aS[col[i]] + ad;
    e = e >= 0.f ? e : 0.2f * e;
    m = fmaxf(m, e);
  }
  for (int off = 32; off; off >>= 1) m = fmaxf(m, __shfl_xor(m, off));
  float sum = 0.f;
  for (int i = s0 + lane; i < s1; i += 64) {
    float e = aS[col[i]] + ad;
    e = e >= 0.f ? e : 0.2f * e;
    sum += expf(e - m);
  }
  for (int off = 32; off; off >>= 1) sum += __shfl_xor(sum, off);
  float denom = sum + 1e-16f;
  float2 acc = make_float2(0.f, 0.f);
  for (int i = s0; i < s1; ++i) {
    int s = col[i];
    float e = aS[s] + ad;
    e = e >= 0.f ? e : 0.2f * e;
    float a = expf(e - m) / denom;
    float2 hv = *(const float2*)&h[(size_t)s * OUTF + lane * 2];
    acc.x += a * hv.x; acc.y += a * hv.y;
  }
  float2 bb = *(const float2*)&bias[lane * 2];
  acc.x += bb.x; acc.y += bb.y;
  *(float2*)&out[(size_t)node * OUTF + lane * 2] = acc;
}

// ---------------- row softmax (+argmax for predictions) ----------------
__global__ __launch_bounds__(256) void softmax_rows(float* __restrict__ x,
                                                    float* __restrict__ pred,
                                                    int n) {
  int node = (blockIdx.x * 256 + threadIdx.x) >> 6;
  int lane = threadIdx.x & 63;
  if (node >= n) return;
  float2 v = *(float2*)&x[(size_t)node * OUTF + lane * 2];
  float bv;
  int bi;
  if (v.y > v.x) { bv = v.y; bi = 2 * lane + 1; }
  else           { bv = v.x; bi = 2 * lane; }
  for (int off = 32; off; off >>= 1) {
    float ov = __shfl_xor(bv, off);
    int oi = __shfl_xor(bi, off);
    if (ov > bv || (ov == bv && oi < bi)) { bv = ov; bi = oi; }
  }
  float e0 = expf(v.x - bv), e1 = expf(v.y - bv);
  float s = e0 + e1;
  for (int off = 32; off; off >>= 1) s += __shfl_xor(s, off);
  float2 r;
  r.x = e0 / s;
  r.y = e1 / s;
  *(float2*)&x[(size_t)node * OUTF + lane * 2] = r;
  if (pred != nullptr && lane == 0) pred[node] = (float)bi;
}

// ---------------- host orchestration ----------------
extern "C" void kernel_launch(void* const* d_in, const int* in_sizes, int n_in,
                              void* d_out, int out_size, void* d_ws, size_t ws_size,
                              hipStream_t stream) {
  const int N = N_NODES, E = E_EDGES;
  const float* x     = (const float*)d_in[0];
  const int*   ei1   = (const int*)d_in[1];
  const int*   ei2   = (const int*)d_in[2];
  const float* W1    = (const float*)d_in[3];
  const float* attS1 = (const float*)d_in[4];
  const float* attD1 = (const float*)d_in[5];
  const float* b1    = (const float*)d_in[6];
  const float* W2    = (const float*)d_in[7];
  const float* attS2 = (const float*)d_in[8];
  const float* attD2 = (const float*)d_in[9];
  const float* b2    = (const float*)d_in[10];
  const float* W3    = (const float*)d_in[11];
  const float* attS3 = (const float*)d_in[12];
  const float* attD3 = (const float*)d_in[13];
  const float* b3    = (const float*)d_in[14];

  char* ws = (char*)d_ws;
  size_t off = 0;
  auto take = [&](size_t bytes) {
    off = (off + 255) & ~(size_t)255;
    size_t o = off;
    off += bytes;
    return o;
  };
  int*   col1 = (int*)(ws + take((size_t)EP_EDGES * 4));
  int*   col2 = (int*)(ws + take((size_t)EP_EDGES * 4));
  int*   rp1  = (int*)(ws + take((size_t)(N + 1) * 4));
  int*   rp2  = (int*)(ws + take((size_t)(N + 1) * 4));
  int*   wp1  = (int*)(ws + take((size_t)N * 4));
  int*   wp2  = (int*)(ws + take((size_t)N * 4));
  int*   flag = (int*)(ws + take(256));
  float* h1h  = (float*)(ws + take((size_t)N * HID * 4));
  float* embh = (float*)(ws + take((size_t)N * HID * 4));
  float* h2   = (float*)(ws + take((size_t)N * OUTF * 4 * 2));
  float* h3   = h2 + (size_t)N * OUTF;
  float* as1  = (float*)(ws + take((size_t)N * 4));
  float* ad1  = (float*)(ws + take((size_t)N * 4));
  float* as2  = (float*)(ws + take((size_t)N * 4));
  float* ad2  = (float*)(ws + take((size_t)N * 4));
  float* as3  = (float*)(ws + take((size_t)N * 4));
  float* ad3  = (float*)(ws + take((size_t)N * 4));

  float* outp = (float*)d_out;
  float* x1   = outp;                         // logits   [N,128]
  float* x2   = outp + (size_t)N * OUTF;      // logits_2 [N,128]
  float* pred = outp + (size_t)2 * N * OUTF;  // predictions [N]

  const int gN = (N + 255) / 256;     // 196
  const int gE = (E + 255) / 256;     // 6250
  const int gW = (N + 3) / 4;         // 12500 (one wave per node)
  const int gM = (N + BM - 1) / BM;   // 782

  // ---- edge dtype detection + CSR build (both graphs) ----
  k_detect<<<1, 256, 0, stream>>>(ei1, flag);

  k_init_deg<<<gN, 256, 0, stream>>>(wp1, N);
  k_count<<<gE, 256, 0, stream>>>(ei1, flag, wp1, E);
  k_scan<<<1, 1024, 0, stream>>>(wp1, rp1, N);
  k_fill_self<<<gN, 256, 0, stream>>>(rp1, wp1, col1, N);
  k_fill_edges<<<gE, 256, 0, stream>>>(ei1, flag, wp1, col1, E);

  k_init_deg<<<gN, 256, 0, stream>>>(wp2, N);
  k_count<<<gE, 256, 0, stream>>>(ei2, flag, wp2, E);
  k_scan<<<1, 1024, 0, stream>>>(wp2, rp2, N);
  k_fill_self<<<gN, 256, 0, stream>>>(rp2, wp2, col2, N);
  k_fill_edges<<<gE, 256, 0, stream>>>(ei2, flag, wp2, col2, E);

  // ---- zero layer-2 K-partial accumulators ----
  hipMemsetAsync(h2, 0, (size_t)N * OUTF * 4 * 2, stream);

  // ---- layer 1, one head at a time (keeps gather working set L3-resident) ----
  for (int h = 0; h < HEADS; ++h) {
    // h1_h = x @ W1[:, h*256 : (h+1)*256]
    gemm_f32<<<dim3(gM, HID / BN), 256, 0, stream>>>(
        x, IN_F, W1 + (size_t)h * HID, HEADS * HID, h1h, HID, N, IN_F, 0);
    // per-node attention dots for this head
    att_dot<HID><<<gW, 256, 0, stream>>>(h1h, attS1 + (size_t)h * HID,
                                         attD1 + (size_t)h * HID, as1, ad1, N);
    // segment softmax + weighted aggregation + bias + ELU -> emb chunk
    aggr_l1<<<gW, 256, 0, stream>>>(rp1, col1, as1, ad1, h1h,
                                    b1 + (size_t)h * HID, embh, N);
    // K-partial GEMMs: h2 += emb_h @ W2[h*256:(h+1)*256, :], same for h3
    gemm_f32<<<dim3(gM, OUTF / BN), 256, 0, stream>>>(
        embh, HID, W2 + (size_t)h * HID * OUTF, OUTF, h2, OUTF, N, HID, 1);
    gemm_f32<<<dim3(gM, OUTF / BN), 256, 0, stream>>>(
        embh, HID, W3 + (size_t)h * HID * OUTF, OUTF, h3, OUTF, N, HID, 1);
  }

  // ---- layer 2 attention + aggregation (heads=1) ----
  att_dot<OUTF><<<gW, 256, 0, stream>>>(h2, attS2, attD2, as2, ad2, N);
  att_dot<OUTF><<<gW, 256, 0, stream>>>(h3, attS3, attD3, as3, ad3, N);
  aggr_l2<<<gW, 256, 0, stream>>>(rp1, col1, as2, ad2, h2, b2, x1, N);
  aggr_l2<<<gW, 256, 0, stream>>>(rp2, col2, as3, ad3, h3, b3, x2, N);

  // ---- softmax rows (+argmax -> predictions) ----
  softmax_rows<<<gW, 256, 0, stream>>>(x1, pred, N);
  softmax_rows<<<gW, 256, 0, stream>>>(x2, nullptr, N);
}

// Round 3
// 4653.305 us; speedup vs baseline: 1.2259x; 1.2259x over previous
//
#include <hip/hip_runtime.h>
#include <hip/hip_bf16.h>
#include <math.h>

#define N_NODES 50000
#define E_EDGES 1600000
#define EP_EDGES (E_EDGES + N_NODES)
#define IN_F 512
#define HID 256
#define HEADS 8
#define OUTF 128

typedef unsigned short u16;
typedef __attribute__((ext_vector_type(8))) short short8;
typedef __attribute__((ext_vector_type(4))) float floatx4;

static __device__ __forceinline__ float eluf(float x) {
  return x > 0.f ? x : expm1f(x);
}

static __device__ __forceinline__ u16 bf16_hi(float v) {
  __hip_bfloat16 h = __float2bfloat16(v);
  return *(u16*)&h;
}
static __device__ __forceinline__ float bf16_f(u16 u) {
  __hip_bfloat16 h = *(__hip_bfloat16*)&u;
  return __bfloat162float(h);
}
// 3-way split: v ~= h + m + l, each bf16 (~24 mantissa bits total)
static __device__ __forceinline__ void split3_bf16(float v, u16& h, u16& m, u16& l) {
  h = bf16_hi(v);
  float r1 = v - bf16_f(h);
  m = bf16_hi(r1);
  float r2 = r1 - bf16_f(m);
  l = bf16_hi(r2);
}

// ---------------- CSR build ----------------

__global__ void k_detect(const int* __restrict__ ei, int* __restrict__ flag) {
  __shared__ int nz;
  if (threadIdx.x == 0) nz = 0;
  __syncthreads();
  for (int i = threadIdx.x; i < 4096; i += blockDim.x)
    if (ei[2 * i + 1] != 0) nz = 1;   // benign race
  __syncthreads();
  if (threadIdx.x == 0) *flag = (nz ? 0 : 1);
}

__global__ void k_init_deg(int* __restrict__ deg, int n) {
  int i = blockIdx.x * 256 + threadIdx.x;
  if (i < n) deg[i] = 1;   // self loop
}

__global__ void k_count(const int* __restrict__ ei, const int* __restrict__ flag,
                        int* __restrict__ deg, int E) {
  int e = blockIdx.x * 256 + threadIdx.x;
  if (e >= E) return;
  int f = *flag;
  int idx = E + e;                       // row 1 = dst
  int dst = ei[f ? 2 * idx : idx];
  atomicAdd(&deg[dst], 1);
}

__global__ __launch_bounds__(1024) void k_scan(const int* __restrict__ deg,
                                               int* __restrict__ rp, int n) {
  __shared__ int sd[1024];
  __shared__ int s_run;
  int tid = threadIdx.x;
  if (tid == 0) s_run = 0;
  __syncthreads();
  for (int base = 0; base < n; base += 1024) {
    int i = base + tid;
    int v = (i < n) ? deg[i] : 0;
    sd[tid] = v;
    __syncthreads();
    for (int off = 1; off < 1024; off <<= 1) {
      int t = (tid >= off) ? sd[tid - off] : 0;
      __syncthreads();
      sd[tid] += t;
      __syncthreads();
    }
    int run = s_run;
    if (i < n) rp[i + 1] = run + sd[tid];
    __syncthreads();
    if (tid == 1023) s_run = run + sd[1023];
    __syncthreads();
  }
  if (tid == 0) rp[0] = 0;
}

__global__ void k_fill_self(const int* __restrict__ rp, int* __restrict__ wp,
                            int* __restrict__ col, int n) {
  int i = blockIdx.x * 256 + threadIdx.x;
  if (i < n) { int p = rp[i]; col[p] = i; wp[i] = p + 1; }
}

__global__ void k_fill_edges(const int* __restrict__ ei, const int* __restrict__ flag,
                             int* __restrict__ wp, int* __restrict__ col, int E) {
  int e = blockIdx.x * 256 + threadIdx.x;
  if (e >= E) return;
  int f = *flag;
  int src = ei[f ? 2 * e : e];
  int didx = E + e;
  int dst = ei[f ? 2 * didx : didx];
  int p = atomicAdd(&wp[dst], 1);
  col[p] = src;
}

// ---------------- weight transpose + 3-way split ----------------
// W[K][Nw] row-major -> H/M/L[Nw][K] row-major. K pow2: kshift/kmask.
__global__ void k_split3_t(const float* __restrict__ W, u16* __restrict__ H,
                           u16* __restrict__ Mv, u16* __restrict__ L,
                           int kshift, int kmask, int Nw, int total) {
  int idx = blockIdx.x * 256 + threadIdx.x;
  if (idx >= total) return;
  int n = idx >> kshift;
  int k = idx & kmask;
  u16 h, m, l;
  split3_bf16(W[(size_t)k * Nw + n], h, m, l);
  H[idx] = h;
  Mv[idx] = m;
  L[idx] = l;
}

// ---------------- split-bf16 MFMA GEMM machinery ----------------
// Tile 128x128, BK=32, 256 threads = 4 waves (2x2), wave = 64x64 via 4x4
// frags of 16x16x32 MFMA. LDS chunk(m,q) at ((m>>4)*64+q*16+(m&15))*8 so a
// wave's frag read lds[(subtile*64+lane)*8] is a conflict-free ds_read_b128.
// LDS element offsets: Ah 0, Am 4096, Al 8192, Bh 12288, Bm 16384, Bl 20480.

#define GBM 128
#define GBN 128
#define GBK 32

#define MFMA_BF16 __builtin_amdgcn_mfma_f32_16x16x32_bf16

__device__ __forceinline__ void gemm_epilogue(floatx4 acc[4][4], float* C,
                                              int ldc, int M, int accum,
                                              int row0, int col0, int wr,
                                              int wc, int lane) {
  int q = lane >> 4, n15 = lane & 15;
#pragma unroll
  for (int i = 0; i < 4; ++i) {
#pragma unroll
    for (int r = 0; r < 4; ++r) {
      int row = row0 + wr * 64 + i * 16 + q * 4 + r;
      if (row < M) {
#pragma unroll
        for (int j = 0; j < 4; ++j) {
          int cg = col0 + wc * 64 + j * 16 + n15;
          float v = acc[i][j][r];
          if (accum) v += C[(size_t)row * ldc + cg];
          C[(size_t)row * ldc + cg] = v;
        }
      }
    }
  }
}

// GEMM1: A = x (fp32, split 3-way on the fly while staging), B pre-split 3-way
// transposed [Nw][K]. 6-term product. C = h1 (fp32), no accumulate.
__global__ __launch_bounds__(256) void gemm1_k(
    const float* __restrict__ X, int lda,
    const u16* __restrict__ Bh, const u16* __restrict__ Bm,
    const u16* __restrict__ Bl, int ldb,
    float* __restrict__ C, int ldc, int M, int K) {
  __shared__ __align__(16) u16 lds[24576];
  int tid = threadIdx.x;
  int lane = tid & 63, wave = tid >> 6;
  int wr = wave >> 1, wc = wave & 1;
  int row0 = blockIdx.x * GBM, col0 = blockIdx.y * GBN;
  floatx4 acc[4][4] = {};
  int m0 = tid >> 2, m1 = (tid + 256) >> 2;
  int q0 = tid & 3;
  int lo0 = ((m0 >> 4) * 64 + q0 * 16 + (m0 & 15)) * 8;
  int lo1 = ((m1 >> 4) * 64 + q0 * 16 + (m1 & 15)) * 8;

  for (int k0 = 0; k0 < K; k0 += GBK) {
    // ---- stage A: fp32 load + in-register 3-way split ----
#pragma unroll
    for (int c = 0; c < 2; ++c) {
      int m = c ? m1 : m0;
      int lo = c ? lo1 : lo0;
      int gr = row0 + m;
      float f[8];
      if (gr < M) {
        float4 f0 = *(const float4*)(X + (size_t)gr * lda + k0 + q0 * 8);
        float4 f1 = *(const float4*)(X + (size_t)gr * lda + k0 + q0 * 8 + 4);
        f[0] = f0.x; f[1] = f0.y; f[2] = f0.z; f[3] = f0.w;
        f[4] = f1.x; f[5] = f1.y; f[6] = f1.z; f[7] = f1.w;
      } else {
#pragma unroll
        for (int e = 0; e < 8; ++e) f[e] = 0.f;
      }
      short8 vh, vm, vl;
#pragma unroll
      for (int e = 0; e < 8; ++e) {
        u16 h, m2, l;
        split3_bf16(f[e], h, m2, l);
        vh[e] = (short)h; vm[e] = (short)m2; vl[e] = (short)l;
      }
      *(short8*)&lds[lo] = vh;
      *(short8*)&lds[4096 + lo] = vm;
      *(short8*)&lds[8192 + lo] = vl;
    }
    // ---- stage B (pre-split, no guard: N dims exact) ----
#pragma unroll
    for (int c = 0; c < 2; ++c) {
      int m = c ? m1 : m0;
      int lo = c ? lo1 : lo0;
      size_t go = (size_t)(col0 + m) * ldb + k0 + q0 * 8;
      *(short8*)&lds[12288 + lo] = *(const short8*)(Bh + go);
      *(short8*)&lds[16384 + lo] = *(const short8*)(Bm + go);
      *(short8*)&lds[20480 + lo] = *(const short8*)(Bl + go);
    }
    __syncthreads();
    short8 a_h[4], a_m[4], a_l[4];
#pragma unroll
    for (int i = 0; i < 4; ++i) {
      int o = ((wr * 4 + i) * 64 + lane) * 8;
      a_h[i] = *(short8*)&lds[o];
      a_m[i] = *(short8*)&lds[4096 + o];
      a_l[i] = *(short8*)&lds[8192 + o];
    }
#pragma unroll
    for (int j = 0; j < 4; ++j) {
      int o = ((wc * 4 + j) * 64 + lane) * 8;
      short8 b_h = *(short8*)&lds[12288 + o];
      short8 b_m = *(short8*)&lds[16384 + o];
      short8 b_l = *(short8*)&lds[20480 + o];
#pragma unroll
      for (int i = 0; i < 4; ++i) {
        acc[i][j] = MFMA_BF16(a_l[i], b_h, acc[i][j], 0, 0, 0);
        acc[i][j] = MFMA_BF16(a_m[i], b_m, acc[i][j], 0, 0, 0);
        acc[i][j] = MFMA_BF16(a_h[i], b_l, acc[i][j], 0, 0, 0);
        acc[i][j] = MFMA_BF16(a_m[i], b_h, acc[i][j], 0, 0, 0);
        acc[i][j] = MFMA_BF16(a_h[i], b_m, acc[i][j], 0, 0, 0);
        acc[i][j] = MFMA_BF16(a_h[i], b_h, acc[i][j], 0, 0, 0);
      }
    }
    __syncthreads();
  }
  gemm_epilogue(acc, C, ldc, M, 0, row0, col0, wr, wc, lane);
}

// 6-term core with pre-split A (used for h2). accumulate.
__device__ __forceinline__ void gemm_core6(
    const u16* __restrict__ Ah, const u16* __restrict__ Am,
    const u16* __restrict__ Al, int lda,
    const u16* __restrict__ Bh, const u16* __restrict__ Bm,
    const u16* __restrict__ Bl, int ldb,
    float* __restrict__ C, int ldc, int M, int K, int row0, int col0,
    u16* lds) {
  int tid = threadIdx.x;
  int lane = tid & 63, wave = tid >> 6;
  int wr = wave >> 1, wc = wave & 1;
  floatx4 acc[4][4] = {};
  int m0 = tid >> 2, m1 = (tid + 256) >> 2;
  int q0 = tid & 3;
  int lo0 = ((m0 >> 4) * 64 + q0 * 16 + (m0 & 15)) * 8;
  int lo1 = ((m1 >> 4) * 64 + q0 * 16 + (m1 & 15)) * 8;
  for (int k0 = 0; k0 < K; k0 += GBK) {
#pragma unroll
    for (int c = 0; c < 2; ++c) {
      int m = c ? m1 : m0;
      int lo = c ? lo1 : lo0;
      int gr = row0 + m;
      short8 vh = {}, vm = {}, vl = {};
      if (gr < M) {
        size_t go = (size_t)gr * lda + k0 + q0 * 8;
        vh = *(const short8*)(Ah + go);
        vm = *(const short8*)(Am + go);
        vl = *(const short8*)(Al + go);
      }
      *(short8*)&lds[lo] = vh;
      *(short8*)&lds[4096 + lo] = vm;
      *(short8*)&lds[8192 + lo] = vl;
      size_t go = (size_t)(col0 + m) * ldb + k0 + q0 * 8;
      *(short8*)&lds[12288 + lo] = *(const short8*)(Bh + go);
      *(short8*)&lds[16384 + lo] = *(const short8*)(Bm + go);
      *(short8*)&lds[20480 + lo] = *(const short8*)(Bl + go);
    }
    __syncthreads();
    short8 a_h[4], a_m[4], a_l[4];
#pragma unroll
    for (int i = 0; i < 4; ++i) {
      int o = ((wr * 4 + i) * 64 + lane) * 8;
      a_h[i] = *(short8*)&lds[o];
      a_m[i] = *(short8*)&lds[4096 + o];
      a_l[i] = *(short8*)&lds[8192 + o];
    }
#pragma unroll
    for (int j = 0; j < 4; ++j) {
      int o = ((wc * 4 + j) * 64 + lane) * 8;
      short8 b_h = *(short8*)&lds[12288 + o];
      short8 b_m = *(short8*)&lds[16384 + o];
      short8 b_l = *(short8*)&lds[20480 + o];
#pragma unroll
      for (int i = 0; i < 4; ++i) {
        acc[i][j] = MFMA_BF16(a_l[i], b_h, acc[i][j], 0, 0, 0);
        acc[i][j] = MFMA_BF16(a_m[i], b_m, acc[i][j], 0, 0, 0);
        acc[i][j] = MFMA_BF16(a_h[i], b_l, acc[i][j], 0, 0, 0);
        acc[i][j] = MFMA_BF16(a_m[i], b_h, acc[i][j], 0, 0, 0);
        acc[i][j] = MFMA_BF16(a_h[i], b_m, acc[i][j], 0, 0, 0);
        acc[i][j] = MFMA_BF16(a_h[i], b_h, acc[i][j], 0, 0, 0);
      }
    }
    __syncthreads();
  }
  gemm_epilogue(acc, C, ldc, M, 1, row0, col0, wr, wc, lane);
}

// 3-term (2-way split) core — used for h3 (no argmax downstream). accumulate.
__device__ __forceinline__ void gemm_core3(
    const u16* __restrict__ Ah, const u16* __restrict__ Am, int lda,
    const u16* __restrict__ Bh, const u16* __restrict__ Bm, int ldb,
    float* __restrict__ C, int ldc, int M, int K, int row0, int col0,
    u16* lds) {
  int tid = threadIdx.x;
  int lane = tid & 63, wave = tid >> 6;
  int wr = wave >> 1, wc = wave & 1;
  floatx4 acc[4][4] = {};
  int m0 = tid >> 2, m1 = (tid + 256) >> 2;
  int q0 = tid & 3;
  int lo0 = ((m0 >> 4) * 64 + q0 * 16 + (m0 & 15)) * 8;
  int lo1 = ((m1 >> 4) * 64 + q0 * 16 + (m1 & 15)) * 8;
  for (int k0 = 0; k0 < K; k0 += GBK) {
#pragma unroll
    for (int c = 0; c < 2; ++c) {
      int m = c ? m1 : m0;
      int lo = c ? lo1 : lo0;
      int gr = row0 + m;
      short8 vh = {}, vm = {};
      if (gr < M) {
        size_t go = (size_t)gr * lda + k0 + q0 * 8;
        vh = *(const short8*)(Ah + go);
        vm = *(const short8*)(Am + go);
      }
      *(short8*)&lds[lo] = vh;
      *(short8*)&lds[4096 + lo] = vm;
      size_t go = (size_t)(col0 + m) * ldb + k0 + q0 * 8;
      *(short8*)&lds[12288 + lo] = *(const short8*)(Bh + go);
      *(short8*)&lds[16384 + lo] = *(const short8*)(Bm + go);
    }
    __syncthreads();
    short8 a_h[4], a_m[4];
#pragma unroll
    for (int i = 0; i < 4; ++i) {
      int o = ((wr * 4 + i) * 64 + lane) * 8;
      a_h[i] = *(short8*)&lds[o];
      a_m[i] = *(short8*)&lds[4096 + o];
    }
#pragma unroll
    for (int j = 0; j < 4; ++j) {
      int o = ((wc * 4 + j) * 64 + lane) * 8;
      short8 b_h = *(short8*)&lds[12288 + o];
      short8 b_m = *(short8*)&lds[16384 + o];
#pragma unroll
      for (int i = 0; i < 4; ++i) {
        acc[i][j] = MFMA_BF16(a_m[i], b_h, acc[i][j], 0, 0, 0);
        acc[i][j] = MFMA_BF16(a_h[i], b_m, acc[i][j], 0, 0, 0);
        acc[i][j] = MFMA_BF16(a_h[i], b_h, acc[i][j], 0, 0, 0);
      }
    }
    __syncthreads();
  }
  gemm_epilogue(acc, C, ldc, M, 1, row0, col0, wr, wc, lane);
}

// GEMM2 (h2, 6-term) and GEMM3 (h3, 3-term) fused via blockIdx.z.
__global__ __launch_bounds__(256) void gemm23_k(
    const u16* __restrict__ Ah, const u16* __restrict__ Am,
    const u16* __restrict__ Al, int lda,
    const u16* __restrict__ B2h, const u16* __restrict__ B2m,
    const u16* __restrict__ B2l,
    const u16* __restrict__ B3h, const u16* __restrict__ B3m, int ldb,
    float* __restrict__ C2, float* __restrict__ C3, int ldc, int M, int K) {
  __shared__ __align__(16) u16 lds[24576];
  if (blockIdx.z == 0)
    gemm_core6(Ah, Am, Al, lda, B2h, B2m, B2l, ldb, C2, ldc, M, K,
               blockIdx.x * GBM, 0, lds);
  else
    gemm_core3(Ah, Am, lda, B3h, B3m, ldb, C3, ldc, M, K,
               blockIdx.x * GBM, 0, lds);
}

// ---------------- attention dot products a_src/a_dst ----------------
template <int C>
__global__ __launch_bounds__(256) void att_dot(
    const float* __restrict__ h, const float* __restrict__ attS,
    const float* __restrict__ attD, float* __restrict__ aS,
    float* __restrict__ aD, int n) {
  int node = (blockIdx.x * 256 + threadIdx.x) >> 6;
  int lane = threadIdx.x & 63;
  if (node >= n) return;
  float s = 0.f, d = 0.f;
  if (C == 256) {
    float4 hv = *(const float4*)&h[(size_t)node * C + lane * 4];
    float4 sv = *(const float4*)&attS[lane * 4];
    float4 dv = *(const float4*)&attD[lane * 4];
    s = hv.x * sv.x + hv.y * sv.y + hv.z * sv.z + hv.w * sv.w;
    d = hv.x * dv.x + hv.y * dv.y + hv.z * dv.z + hv.w * dv.w;
  } else {
    float2 hv = *(const float2*)&h[(size_t)node * C + lane * 2];
    float2 sv = *(const float2*)&attS[lane * 2];
    float2 dv = *(const float2*)&attD[lane * 2];
    s = hv.x * sv.x + hv.y * sv.y;
    d = hv.x * dv.x + hv.y * dv.y;
  }
  for (int off = 32; off; off >>= 1) {
    s += __shfl_xor(s, off);
    d += __shfl_xor(d, off);
  }
  if (lane == 0) { aS[node] = s; aD[node] = d; }
}

// ---------------- per-edge alpha (segment softmax) ----------------
__global__ __launch_bounds__(256) void compute_alpha(
    const int* __restrict__ rp, const int* __restrict__ col,
    const float* __restrict__ aS, const float* __restrict__ aD,
    float* __restrict__ alpha, int n) {
  int node = (blockIdx.x * 256 + threadIdx.x) >> 6;
  int lane = threadIdx.x & 63;
  if (node >= n) return;
  int s0 = rp[node], s1 = rp[node + 1];
  float ad = aD[node];
  float m = -3.0e38f;
  for (int i = s0 + lane; i < s1; i += 64) {
    float e = aS[col[i]] + ad;
    e = e >= 0.f ? e : 0.2f * e;
    m = fmaxf(m, e);
  }
  for (int off = 32; off; off >>= 1) m = fmaxf(m, __shfl_xor(m, off));
  float sum = 0.f;
  for (int i = s0 + lane; i < s1; i += 64) {
    float e = aS[col[i]] + ad;
    e = e >= 0.f ? e : 0.2f * e;
    sum += expf(e - m);
  }
  for (int off = 32; off; off >>= 1) sum += __shfl_xor(sum, off);
  float inv = 1.f / (sum + 1e-16f);
  for (int i = s0 + lane; i < s1; i += 64) {
    float e = aS[col[i]] + ad;
    e = e >= 0.f ? e : 0.2f * e;
    alpha[i] = expf(e - m) * inv;
  }
}

// ---------------- layer-1 gather-aggregate ----------------
// one wave per node; epilogue fuses +bias, ELU, 3-way bf16 split of emb.
__global__ __launch_bounds__(256) void aggr_gather(
    const int* __restrict__ rp, const int* __restrict__ col,
    const float* __restrict__ alpha, const float* __restrict__ h,
    const float* __restrict__ bias, u16* __restrict__ embH,
    u16* __restrict__ embM, u16* __restrict__ embL, int n) {
  int node = (blockIdx.x * 256 + threadIdx.x) >> 6;
  int lane = threadIdx.x & 63;
  if (node >= n) return;
  int s0 = rp[node], s1 = rp[node + 1];
  float4 acc = make_float4(0.f, 0.f, 0.f, 0.f);
  int i = s0;
  for (; i + 4 <= s1; i += 4) {
    int c0 = col[i], c1 = col[i + 1], c2 = col[i + 2], c3 = col[i + 3];
    float a0 = alpha[i], a1 = alpha[i + 1], a2 = alpha[i + 2], a3 = alpha[i + 3];
    float4 h0 = *(const float4*)&h[(size_t)c0 * HID + lane * 4];
    float4 h1 = *(const float4*)&h[(size_t)c1 * HID + lane * 4];
    float4 h2 = *(const float4*)&h[(size_t)c2 * HID + lane * 4];
    float4 h3 = *(const float4*)&h[(size_t)c3 * HID + lane * 4];
    acc.x += a0 * h0.x + a1 * h1.x + a2 * h2.x + a3 * h3.x;
    acc.y += a0 * h0.y + a1 * h1.y + a2 * h2.y + a3 * h3.y;
    acc.z += a0 * h0.z + a1 * h1.z + a2 * h2.z + a3 * h3.z;
    acc.w += a0 * h0.w + a1 * h1.w + a2 * h2.w + a3 * h3.w;
  }
  for (; i < s1; ++i) {
    int c = col[i];
    float a = alpha[i];
    float4 hv = *(const float4*)&h[(size_t)c * HID + lane * 4];
    acc.x += a * hv.x; acc.y += a * hv.y; acc.z += a * hv.z; acc.w += a * hv.w;
  }
  float4 bb = *(const float4*)&bias[lane * 4];
  float v0 = eluf(acc.x + bb.x);
  float v1 = eluf(acc.y + bb.y);
  float v2 = eluf(acc.z + bb.z);
  float v3 = eluf(acc.w + bb.w);
  ushort4 uh, um, ul;
  split3_bf16(v0, uh.x, um.x, ul.x);
  split3_bf16(v1, uh.y, um.y, ul.y);
  split3_bf16(v2, uh.z, um.z, ul.z);
  split3_bf16(v3, uh.w, um.w, ul.w);
  size_t o = (size_t)node * HID + lane * 4;
  *(ushort4*)&embH[o] = uh;
  *(ushort4*)&embM[o] = um;
  *(ushort4*)&embL[o] = ul;
}

// ---------------- layer-2 aggregation (C=128, fp32) ----------------
__global__ __launch_bounds__(256) void aggr_l2(
    const int* __restrict__ rp, const int* __restrict__ col,
    const float* __restrict__ aS, const float* __restrict__ aD,
    const float* __restrict__ h, const float* __restrict__ bias,
    float* __restrict__ out, int n) {
  int node = (blockIdx.x * 256 + threadIdx.x) >> 6;
  int lane = threadIdx.x & 63;
  if (node >= n) return;
  int s0 = rp[node], s1 = rp[node + 1];
  float ad = aD[node];
  float m = -3.0e38f;
  for (int i = s0 + lane; i < s1; i += 64) {
    float e = aS[col[i]] + ad;
    e = e >= 0.f ? e : 0.2f * e;
    m = fmaxf(m, e);
  }
  for (int off = 32; off; off >>= 1) m = fmaxf(m, __shfl_xor(m, off));
  float sum = 0.f;
  for (int i = s0 + lane; i < s1; i += 64) {
    float e = aS[col[i]] + ad;
    e = e >= 0.f ? e : 0.2f * e;
    sum += expf(e - m);
  }
  for (int off = 32; off; off >>= 1) sum += __shfl_xor(sum, off);
  float denom = sum + 1e-16f;
  float2 acc = make_float2(0.f, 0.f);
  for (int i = s0; i < s1; ++i) {
    int s = col[i];
    float e = aS[s] + ad;
    e = e >= 0.f ? e : 0.2f * e;
    float a = expf(e - m) / denom;
    float2 hv = *(const float2*)&h[(size_t)s * OUTF + lane * 2];
    acc.x += a * hv.x; acc.y += a * hv.y;
  }
  float2 bb = *(const float2*)&bias[lane * 2];
  acc.x += bb.x; acc.y += bb.y;
  *(float2*)&out[(size_t)node * OUTF + lane * 2] = acc;
}

// ---------------- row softmax (+argmax for predictions) ----------------
__global__ __launch_bounds__(256) void softmax_rows(float* __restrict__ x,
                                                    float* __restrict__ pred,
                                                    int n) {
  int node = (blockIdx.x * 256 + threadIdx.x) >> 6;
  int lane = threadIdx.x & 63;
  if (node >= n) return;
  float2 v = *(float2*)&x[(size_t)node * OUTF + lane * 2];
  float bv;
  int bi;
  if (v.y > v.x) { bv = v.y; bi = 2 * lane + 1; }
  else           { bv = v.x; bi = 2 * lane; }
  for (int off = 32; off; off >>= 1) {
    float ov = __shfl_xor(bv, off);
    int oi = __shfl_xor(bi, off);
    if (ov > bv || (ov == bv && oi < bi)) { bv = ov; bi = oi; }
  }
  float e0 = expf(v.x - bv), e1 = expf(v.y - bv);
  float s = e0 + e1;
  for (int off = 32; off; off >>= 1) s += __shfl_xor(s, off);
  float2 r;
  r.x = e0 / s;
  r.y = e1 / s;
  *(float2*)&x[(size_t)node * OUTF + lane * 2] = r;
  if (pred != nullptr && lane == 0) pred[node] = (float)bi;
}

// ---------------- host orchestration ----------------
extern "C" void kernel_launch(void* const* d_in, const int* in_sizes, int n_in,
                              void* d_out, int out_size, void* d_ws, size_t ws_size,
                              hipStream_t stream) {
  const int N = N_NODES, E = E_EDGES;
  const float* x     = (const float*)d_in[0];
  const int*   ei1   = (const int*)d_in[1];
  const int*   ei2   = (const int*)d_in[2];
  const float* W1    = (const float*)d_in[3];
  const float* attS1 = (const float*)d_in[4];
  const float* attD1 = (const float*)d_in[5];
  const float* b1    = (const float*)d_in[6];
  const float* W2    = (const float*)d_in[7];
  const float* attS2 = (const float*)d_in[8];
  const float* attD2 = (const float*)d_in[9];
  const float* b2    = (const float*)d_in[10];
  const float* W3    = (const float*)d_in[11];
  const float* attS3 = (const float*)d_in[12];
  const float* attD3 = (const float*)d_in[13];
  const float* b3    = (const float*)d_in[14];

  char* ws = (char*)d_ws;
  size_t off = 0;
  auto take = [&](size_t bytes) {
    off = (off + 255) & ~(size_t)255;
    size_t o = off;
    off += bytes;
    return o;
  };
  int*   col1 = (int*)(ws + take((size_t)EP_EDGES * 4));
  int*   col2 = (int*)(ws + take((size_t)EP_EDGES * 4));
  int*   rp1  = (int*)(ws + take((size_t)(N + 1) * 4));
  int*   rp2  = (int*)(ws + take((size_t)(N + 1) * 4));
  int*   wp1  = (int*)(ws + take((size_t)N * 4));
  int*   wp2  = (int*)(ws + take((size_t)N * 4));
  int*   flag = (int*)(ws + take(256));
  float* h1h  = (float*)(ws + take((size_t)N * HID * 4));       // 51.2 MB
  u16*   embH = (u16*)(ws + take((size_t)N * HID * 2));         // 25.6 MB x3
  u16*   embM = (u16*)(ws + take((size_t)N * HID * 2));
  u16*   embL = (u16*)(ws + take((size_t)N * HID * 2));
  float* h2   = (float*)(ws + take((size_t)N * OUTF * 4 * 2));  // h2+h3
  float* h3   = h2 + (size_t)N * OUTF;
  float* alpha= (float*)(ws + take((size_t)EP_EDGES * 4));      // 6.6 MB
  u16*   W1Th = (u16*)(ws + take((size_t)IN_F * HID * HEADS * 2));  // [2048][512]
  u16*   W1Tm = (u16*)(ws + take((size_t)IN_F * HID * HEADS * 2));
  u16*   W1Tl = (u16*)(ws + take((size_t)IN_F * HID * HEADS * 2));
  u16*   W2Th = (u16*)(ws + take((size_t)HID * HEADS * OUTF * 2)); // [128][2048]
  u16*   W2Tm = (u16*)(ws + take((size_t)HID * HEADS * OUTF * 2));
  u16*   W2Tl = (u16*)(ws + take((size_t)HID * HEADS * OUTF * 2));
  u16*   W3Th = (u16*)(ws + take((size_t)HID * HEADS * OUTF * 2));
  u16*   W3Tm = (u16*)(ws + take((size_t)HID * HEADS * OUTF * 2));
  float* as1  = (float*)(ws + take((size_t)N * 4));
  float* ad1  = (float*)(ws + take((size_t)N * 4));
  float* as2  = (float*)(ws + take((size_t)N * 4));
  float* ad2  = (float*)(ws + take((size_t)N * 4));
  float* as3  = (float*)(ws + take((size_t)N * 4));
  float* ad3  = (float*)(ws + take((size_t)N * 4));

  float* outp = (float*)d_out;
  float* x1   = outp;                         // logits   [N,128]
  float* x2   = outp + (size_t)N * OUTF;      // logits_2 [N,128]
  float* pred = outp + (size_t)2 * N * OUTF;  // predictions [N]

  const int gN = (N + 255) / 256;
  const int gE = (E + 255) / 256;
  const int gW = (N + 3) / 4;                 // one wave per node
  const int gM = (N + GBM - 1) / GBM;         // 391

  // ---- weight transpose + 3-way splits ----
  k_split3_t<<<(IN_F * HID * HEADS + 255) / 256, 256, 0, stream>>>(
      W1, W1Th, W1Tm, W1Tl, 9, 511, HID * HEADS, IN_F * HID * HEADS);
  k_split3_t<<<(HID * HEADS * OUTF + 255) / 256, 256, 0, stream>>>(
      W2, W2Th, W2Tm, W2Tl, 11, 2047, OUTF, HID * HEADS * OUTF);
  k_split3_t<<<(HID * HEADS * OUTF + 255) / 256, 256, 0, stream>>>(
      W3, W3Th, W3Tm, W3Tm /*l unused for 3-term; reuse m as dummy*/, 11, 2047,
      OUTF, HID * HEADS * OUTF);

  // ---- edge dtype detection + CSR build (both graphs) ----
  k_detect<<<1, 256, 0, stream>>>(ei1, flag);

  k_init_deg<<<gN, 256, 0, stream>>>(wp1, N);
  k_count<<<gE, 256, 0, stream>>>(ei1, flag, wp1, E);
  k_scan<<<1, 1024, 0, stream>>>(wp1, rp1, N);
  k_fill_self<<<gN, 256, 0, stream>>>(rp1, wp1, col1, N);
  k_fill_edges<<<gE, 256, 0, stream>>>(ei1, flag, wp1, col1, E);

  k_init_deg<<<gN, 256, 0, stream>>>(wp2, N);
  k_count<<<gE, 256, 0, stream>>>(ei2, flag, wp2, E);
  k_scan<<<1, 1024, 0, stream>>>(wp2, rp2, N);
  k_fill_self<<<gN, 256, 0, stream>>>(rp2, wp2, col2, N);
  k_fill_edges<<<gE, 256, 0, stream>>>(ei2, flag, wp2, col2, E);

  // ---- zero layer-2 K-partial accumulators ----
  hipMemsetAsync(h2, 0, (size_t)N * OUTF * 4 * 2, stream);

  // ---- layer 1, one head at a time ----
  for (int h = 0; h < HEADS; ++h) {
    gemm1_k<<<dim3(gM, HID / GBN), 256, 0, stream>>>(
        x, IN_F,
        W1Th + (size_t)h * HID * IN_F, W1Tm + (size_t)h * HID * IN_F,
        W1Tl + (size_t)h * HID * IN_F, IN_F, h1h, HID, N, IN_F);
    att_dot<HID><<<gW, 256, 0, stream>>>(h1h, attS1 + (size_t)h * HID,
                                         attD1 + (size_t)h * HID, as1, ad1, N);
    compute_alpha<<<gW, 256, 0, stream>>>(rp1, col1, as1, ad1, alpha, N);
    aggr_gather<<<gW, 256, 0, stream>>>(rp1, col1, alpha, h1h,
                                        b1 + (size_t)h * HID, embH, embM, embL, N);
    gemm23_k<<<dim3(gM, 1, 2), 256, 0, stream>>>(
        embH, embM, embL, HID,
        W2Th + (size_t)h * HID, W2Tm + (size_t)h * HID, W2Tl + (size_t)h * HID,
        W3Th + (size_t)h * HID, W3Tm + (size_t)h * HID, HID * HEADS,
        h2, h3, OUTF, N, HID);
  }

  // ---- layer 2 attention + aggregation (heads=1) ----
  att_dot<OUTF><<<gW, 256, 0, stream>>>(h2, attS2, attD2, as2, ad2, N);
  att_dot<OUTF><<<gW, 256, 0, stream>>>(h3, attS3, attD3, as3, ad3, N);
  aggr_l2<<<gW, 256, 0, stream>>>(rp1, col1, as2, ad2, h2, b2, x1, N);
  aggr_l2<<<gW, 256, 0, stream>>>(rp2, col2, as3, ad3, h3, b3, x2, N);

  // ---- softmax rows (+argmax -> predictions) ----
  softmax_rows<<<gW, 256, 0, stream>>>(x1, pred, N);
  softmax_rows<<<gW, 256, 0, stream>>>(x2, nullptr, N);
}

// Round 7
// 4334.870 us; speedup vs baseline: 1.3160x; 1.0735x over previous
//
#include <hip/hip_runtime.h>
#include <hip/hip_bf16.h>
#include <math.h>

#define N_NODES 50000
#define E_EDGES 1600000
#define EP_EDGES (E_EDGES + N_NODES)
#define IN_F 512
#define HID 256
#define HEADS 8
#define OUTF 128

typedef unsigned short u16;
typedef __attribute__((ext_vector_type(8))) short short8;
typedef __attribute__((ext_vector_type(4))) float floatx4;

static __device__ __forceinline__ float eluf(float x) {
  return x > 0.f ? x : expm1f(x);
}

static __device__ __forceinline__ u16 bf16_hi(float v) {
  __hip_bfloat16 h = __float2bfloat16(v);
  return *(u16*)&h;
}
static __device__ __forceinline__ float bf16_f(u16 u) {
  __hip_bfloat16 h = *(__hip_bfloat16*)&u;
  return __bfloat162float(h);
}
// 3-way split: v ~= h + m + l, each bf16 (~24 mantissa bits total)
static __device__ __forceinline__ void split3_bf16(float v, u16& h, u16& m, u16& l) {
  h = bf16_hi(v);
  float r1 = v - bf16_f(h);
  m = bf16_hi(r1);
  float r2 = r1 - bf16_f(m);
  l = bf16_hi(r2);
}

// clamp index to [0, n)
static __device__ __forceinline__ int clampi(int v, int n) {
  return v < 0 ? 0 : (v >= n ? n - 1 : v);
}

// ---------------- CSR build ----------------

__global__ void k_detect(const int* __restrict__ ei, int* __restrict__ flag) {
  __shared__ int nz;
  if (threadIdx.x == 0) nz = 0;
  __syncthreads();
  for (int i = threadIdx.x; i < 4096; i += blockDim.x)
    if (ei[2 * i + 1] != 0) nz = 1;   // benign race
  __syncthreads();
  if (threadIdx.x == 0) *flag = (nz ? 0 : 1);
}

__global__ void k_init_deg(int* __restrict__ deg, int n) {
  int i = blockIdx.x * 256 + threadIdx.x;
  if (i < n) deg[i] = 1;   // self loop
}

__global__ void k_count(const int* __restrict__ ei, const int* __restrict__ flag,
                        int* __restrict__ deg, int E) {
  int e = blockIdx.x * 256 + threadIdx.x;
  if (e >= E) return;
  int f = *flag;
  int idx = E + e;                       // row 1 = dst
  int dst = clampi(ei[f ? 2 * idx : idx], N_NODES);
  atomicAdd(&deg[dst], 1);
}

__global__ __launch_bounds__(1024) void k_scan(const int* __restrict__ deg,
                                               int* __restrict__ rp, int n) {
  __shared__ int sd[1024];
  __shared__ int s_run;
  int tid = threadIdx.x;
  if (tid == 0) s_run = 0;
  __syncthreads();
  for (int base = 0; base < n; base += 1024) {
    int i = base + tid;
    int v = (i < n) ? deg[i] : 0;
    sd[tid] = v;
    __syncthreads();
    for (int off = 1; off < 1024; off <<= 1) {
      int t = (tid >= off) ? sd[tid - off] : 0;
      __syncthreads();
      sd[tid] += t;
      __syncthreads();
    }
    int run = s_run;
    if (i < n) rp[i + 1] = run + sd[tid];
    __syncthreads();
    if (tid == 1023) s_run = run + sd[1023];
    __syncthreads();
  }
  if (tid == 0) rp[0] = 0;
}

__global__ void k_fill_self(const int* __restrict__ rp, int* __restrict__ wp,
                            int* __restrict__ col, int n) {
  int i = blockIdx.x * 256 + threadIdx.x;
  if (i < n) { int p = rp[i]; col[p] = i; wp[i] = p + 1; }
}

__global__ void k_fill_edges(const int* __restrict__ ei, const int* __restrict__ flag,
                             int* __restrict__ wp, int* __restrict__ col, int E) {
  int e = blockIdx.x * 256 + threadIdx.x;
  if (e >= E) return;
  int f = *flag;
  int src = clampi(ei[f ? 2 * e : e], N_NODES);
  int didx = E + e;
  int dst = clampi(ei[f ? 2 * didx : didx], N_NODES);
  int p = atomicAdd(&wp[dst], 1);
  col[p] = src;
}

// ---------------- weight transpose + 3-way split ----------------
// W[K][Nw] row-major -> H/M/L[Nw][K] row-major. K pow2: kshift/kmask.
__global__ void k_split3_t(const float* __restrict__ W, u16* __restrict__ H,
                           u16* __restrict__ Mv, u16* __restrict__ L,
                           int kshift, int kmask, int Nw, int total) {
  int idx = blockIdx.x * 256 + threadIdx.x;
  if (idx >= total) return;
  int n = idx >> kshift;
  int k = idx & kmask;
  u16 h, m, l;
  split3_bf16(W[(size_t)k * Nw + n], h, m, l);
  H[idx] = h;
  Mv[idx] = m;
  L[idx] = l;
}

// ---------------- split-bf16 MFMA GEMM machinery ----------------
// Tile 128x128, BK=32, 256 threads = 4 waves (2x2), wave = 64x64 via 4x4
// frags of 16x16x32 MFMA. LDS chunk(m,q) at ((m>>4)*64+q*16+(m&15))*8 so a
// wave's frag read lds[(subtile*64+lane)*8] is a conflict-free ds_read_b128.
// LDS element offsets: Ah 0, Am 4096, Al 8192, Bh 12288, Bm 16384, Bl 20480.

#define GBM 128
#define GBN 128
#define GBK 32

#define MFMA_BF16 __builtin_amdgcn_mfma_f32_16x16x32_bf16

__device__ __forceinline__ void gemm_epilogue(floatx4 acc[4][4], float* C,
                                              int ldc, int M, int accum,
                                              int row0, int col0, int wr,
                                              int wc, int lane) {
  int q = lane >> 4, n15 = lane & 15;
#pragma unroll
  for (int i = 0; i < 4; ++i) {
#pragma unroll
    for (int r = 0; r < 4; ++r) {
      int row = row0 + wr * 64 + i * 16 + q * 4 + r;
      if (row < M) {
#pragma unroll
        for (int j = 0; j < 4; ++j) {
          int cg = col0 + wc * 64 + j * 16 + n15;
          float v = acc[i][j][r];
          if (accum) v += C[(size_t)row * ldc + cg];
          C[(size_t)row * ldc + cg] = v;
        }
      }
    }
  }
}

// GEMM1: A = x (fp32, split 3-way on the fly while staging), B pre-split 3-way
// transposed [Nw][K]. 6-term product. C = h1 (fp32), no accumulate.
__global__ __launch_bounds__(256) void gemm1_k(
    const float* __restrict__ X, int lda,
    const u16* __restrict__ Bh, const u16* __restrict__ Bm,
    const u16* __restrict__ Bl, int ldb,
    float* __restrict__ C, int ldc, int M, int K) {
  __shared__ __align__(16) u16 lds[24576];
  int tid = threadIdx.x;
  int lane = tid & 63, wave = tid >> 6;
  int wr = wave >> 1, wc = wave & 1;
  int row0 = blockIdx.x * GBM, col0 = blockIdx.y * GBN;
  floatx4 acc[4][4] = {};
  int m0 = tid >> 2, m1 = (tid + 256) >> 2;
  int q0 = tid & 3;
  int lo0 = ((m0 >> 4) * 64 + q0 * 16 + (m0 & 15)) * 8;
  int lo1 = ((m1 >> 4) * 64 + q0 * 16 + (m1 & 15)) * 8;

  for (int k0 = 0; k0 < K; k0 += GBK) {
    // ---- stage A: fp32 load + in-register 3-way split ----
#pragma unroll
    for (int c = 0; c < 2; ++c) {
      int m = c ? m1 : m0;
      int lo = c ? lo1 : lo0;
      int gr = row0 + m;
      float f[8];
      if (gr < M) {
        float4 f0 = *(const float4*)(X + (size_t)gr * lda + k0 + q0 * 8);
        float4 f1 = *(const float4*)(X + (size_t)gr * lda + k0 + q0 * 8 + 4);
        f[0] = f0.x; f[1] = f0.y; f[2] = f0.z; f[3] = f0.w;
        f[4] = f1.x; f[5] = f1.y; f[6] = f1.z; f[7] = f1.w;
      } else {
#pragma unroll
        for (int e = 0; e < 8; ++e) f[e] = 0.f;
      }
      short8 vh, vm, vl;
#pragma unroll
      for (int e = 0; e < 8; ++e) {
        u16 h, m2, l;
        split3_bf16(f[e], h, m2, l);
        vh[e] = (short)h; vm[e] = (short)m2; vl[e] = (short)l;
      }
      *(short8*)&lds[lo] = vh;
      *(short8*)&lds[4096 + lo] = vm;
      *(short8*)&lds[8192 + lo] = vl;
    }
    // ---- stage B (pre-split, no guard: N dims exact) ----
#pragma unroll
    for (int c = 0; c < 2; ++c) {
      int m = c ? m1 : m0;
      int lo = c ? lo1 : lo0;
      size_t go = (size_t)(col0 + m) * ldb + k0 + q0 * 8;
      *(short8*)&lds[12288 + lo] = *(const short8*)(Bh + go);
      *(short8*)&lds[16384 + lo] = *(const short8*)(Bm + go);
      *(short8*)&lds[20480 + lo] = *(const short8*)(Bl + go);
    }
    __syncthreads();
    short8 a_h[4], a_m[4], a_l[4];
#pragma unroll
    for (int i = 0; i < 4; ++i) {
      int o = ((wr * 4 + i) * 64 + lane) * 8;
      a_h[i] = *(short8*)&lds[o];
      a_m[i] = *(short8*)&lds[4096 + o];
      a_l[i] = *(short8*)&lds[8192 + o];
    }
#pragma unroll
    for (int j = 0; j < 4; ++j) {
      int o = ((wc * 4 + j) * 64 + lane) * 8;
      short8 b_h = *(short8*)&lds[12288 + o];
      short8 b_m = *(short8*)&lds[16384 + o];
      short8 b_l = *(short8*)&lds[20480 + o];
#pragma unroll
      for (int i = 0; i < 4; ++i) {
        acc[i][j] = MFMA_BF16(a_l[i], b_h, acc[i][j], 0, 0, 0);
        acc[i][j] = MFMA_BF16(a_m[i], b_m, acc[i][j], 0, 0, 0);
        acc[i][j] = MFMA_BF16(a_h[i], b_l, acc[i][j], 0, 0, 0);
        acc[i][j] = MFMA_BF16(a_m[i], b_h, acc[i][j], 0, 0, 0);
        acc[i][j] = MFMA_BF16(a_h[i], b_m, acc[i][j], 0, 0, 0);
        acc[i][j] = MFMA_BF16(a_h[i], b_h, acc[i][j], 0, 0, 0);
      }
    }
    __syncthreads();
  }
  gemm_epilogue(acc, C, ldc, M, 0, row0, col0, wr, wc, lane);
}

// 6-term core with pre-split A (used for h2). accumulate.
__device__ __forceinline__ void gemm_core6(
    const u16* __restrict__ Ah, const u16* __restrict__ Am,
    const u16* __restrict__ Al, int lda,
    const u16* __restrict__ Bh, const u16* __restrict__ Bm,
    const u16* __restrict__ Bl, int ldb,
    float* __restrict__ C, int ldc, int M, int K, int row0, int col0,
    u16* lds) {
  int tid = threadIdx.x;
  int lane = tid & 63, wave = tid >> 6;
  int wr = wave >> 1, wc = wave & 1;
  floatx4 acc[4][4] = {};
  int m0 = tid >> 2, m1 = (tid + 256) >> 2;
  int q0 = tid & 3;
  int lo0 = ((m0 >> 4) * 64 + q0 * 16 + (m0 & 15)) * 8;
  int lo1 = ((m1 >> 4) * 64 + q0 * 16 + (m1 & 15)) * 8;
  for (int k0 = 0; k0 < K; k0 += GBK) {
#pragma unroll
    for (int c = 0; c < 2; ++c) {
      int m = c ? m1 : m0;
      int lo = c ? lo1 : lo0;
      int gr = row0 + m;
      short8 vh = {}, vm = {}, vl = {};
      if (gr < M) {
        size_t go = (size_t)gr * lda + k0 + q0 * 8;
        vh = *(const short8*)(Ah + go);
        vm = *(const short8*)(Am + go);
        vl = *(const short8*)(Al + go);
      }
      *(short8*)&lds[lo] = vh;
      *(short8*)&lds[4096 + lo] = vm;
      *(short8*)&lds[8192 + lo] = vl;
      size_t go = (size_t)(col0 + m) * ldb + k0 + q0 * 8;
      *(short8*)&lds[12288 + lo] = *(const short8*)(Bh + go);
      *(short8*)&lds[16384 + lo] = *(const short8*)(Bm + go);
      *(short8*)&lds[20480 + lo] = *(const short8*)(Bl + go);
    }
    __syncthreads();
    short8 a_h[4], a_m[4], a_l[4];
#pragma unroll
    for (int i = 0; i < 4; ++i) {
      int o = ((wr * 4 + i) * 64 + lane) * 8;
      a_h[i] = *(short8*)&lds[o];
      a_m[i] = *(short8*)&lds[4096 + o];
      a_l[i] = *(short8*)&lds[8192 + o];
    }
#pragma unroll
    for (int j = 0; j < 4; ++j) {
      int o = ((wc * 4 + j) * 64 + lane) * 8;
      short8 b_h = *(short8*)&lds[12288 + o];
      short8 b_m = *(short8*)&lds[16384 + o];
      short8 b_l = *(short8*)&lds[20480 + o];
#pragma unroll
      for (int i = 0; i < 4; ++i) {
        acc[i][j] = MFMA_BF16(a_l[i], b_h, acc[i][j], 0, 0, 0);
        acc[i][j] = MFMA_BF16(a_m[i], b_m, acc[i][j], 0, 0, 0);
        acc[i][j] = MFMA_BF16(a_h[i], b_l, acc[i][j], 0, 0, 0);
        acc[i][j] = MFMA_BF16(a_m[i], b_h, acc[i][j], 0, 0, 0);
        acc[i][j] = MFMA_BF16(a_h[i], b_m, acc[i][j], 0, 0, 0);
        acc[i][j] = MFMA_BF16(a_h[i], b_h, acc[i][j], 0, 0, 0);
      }
    }
    __syncthreads();
  }
  gemm_epilogue(acc, C, ldc, M, 1, row0, col0, wr, wc, lane);
}

// 3-term (2-way split) core — used for h3 (no argmax downstream). accumulate.
__device__ __forceinline__ void gemm_core3(
    const u16* __restrict__ Ah, const u16* __restrict__ Am, int lda,
    const u16* __restrict__ Bh, const u16* __restrict__ Bm, int ldb,
    float* __restrict__ C, int ldc, int M, int K, int row0, int col0,
    u16* lds) {
  int tid = threadIdx.x;
  int lane = tid & 63, wave = tid >> 6;
  int wr = wave >> 1, wc = wave & 1;
  floatx4 acc[4][4] = {};
  int m0 = tid >> 2, m1 = (tid + 256) >> 2;
  int q0 = tid & 3;
  int lo0 = ((m0 >> 4) * 64 + q0 * 16 + (m0 & 15)) * 8;
  int lo1 = ((m1 >> 4) * 64 + q0 * 16 + (m1 & 15)) * 8;
  for (int k0 = 0; k0 < K; k0 += GBK) {
#pragma unroll
    for (int c = 0; c < 2; ++c) {
      int m = c ? m1 : m0;
      int lo = c ? lo1 : lo0;
      int gr = row0 + m;
      short8 vh = {}, vm = {};
      if (gr < M) {
        size_t go = (size_t)gr * lda + k0 + q0 * 8;
        vh = *(const short8*)(Ah + go);
        vm = *(const short8*)(Am + go);
      }
      *(short8*)&lds[lo] = vh;
      *(short8*)&lds[4096 + lo] = vm;
      size_t go = (size_t)(col0 + m) * ldb + k0 + q0 * 8;
      *(short8*)&lds[12288 + lo] = *(const short8*)(Bh + go);
      *(short8*)&lds[16384 + lo] = *(const short8*)(Bm + go);
    }
    __syncthreads();
    short8 a_h[4], a_m[4];
#pragma unroll
    for (int i = 0; i < 4; ++i) {
      int o = ((wr * 4 + i) * 64 + lane) * 8;
      a_h[i] = *(short8*)&lds[o];
      a_m[i] = *(short8*)&lds[4096 + o];
    }
#pragma unroll
    for (int j = 0; j < 4; ++j) {
      int o = ((wc * 4 + j) * 64 + lane) * 8;
      short8 b_h = *(short8*)&lds[12288 + o];
      short8 b_m = *(short8*)&lds[16384 + o];
#pragma unroll
      for (int i = 0; i < 4; ++i) {
        acc[i][j] = MFMA_BF16(a_m[i], b_h, acc[i][j], 0, 0, 0);
        acc[i][j] = MFMA_BF16(a_h[i], b_m, acc[i][j], 0, 0, 0);
        acc[i][j] = MFMA_BF16(a_h[i], b_h, acc[i][j], 0, 0, 0);
      }
    }
    __syncthreads();
  }
  gemm_epilogue(acc, C, ldc, M, 1, row0, col0, wr, wc, lane);
}

// GEMM2 (h2, 6-term) and GEMM3 (h3, 3-term) fused via blockIdx.z.
__global__ __launch_bounds__(256) void gemm23_k(
    const u16* __restrict__ Ah, const u16* __restrict__ Am,
    const u16* __restrict__ Al, int lda,
    const u16* __restrict__ B2h, const u16* __restrict__ B2m,
    const u16* __restrict__ B2l,
    const u16* __restrict__ B3h, const u16* __restrict__ B3m, int ldb,
    float* __restrict__ C2, float* __restrict__ C3, int ldc, int M, int K) {
  __shared__ __align__(16) u16 lds[24576];
  if (blockIdx.z == 0)
    gemm_core6(Ah, Am, Al, lda, B2h, B2m, B2l, ldb, C2, ldc, M, K,
               blockIdx.x * GBM, 0, lds);
  else
    gemm_core3(Ah, Am, lda, B3h, B3m, ldb, C3, ldc, M, K,
               blockIdx.x * GBM, 0, lds);
}

// ---------------- attention dot products a_src/a_dst ----------------
template <int C>
__global__ __launch_bounds__(256) void att_dot(
    const float* __restrict__ h, const float* __restrict__ attS,
    const float* __restrict__ attD, float* __restrict__ aS,
    float* __restrict__ aD, int n) {
  int node = (blockIdx.x * 256 + threadIdx.x) >> 6;
  int lane = threadIdx.x & 63;
  if (node >= n) return;
  float s = 0.f, d = 0.f;
  if (C == 256) {
    float4 hv = *(const float4*)&h[(size_t)node * C + lane * 4];
    float4 sv = *(const float4*)&attS[lane * 4];
    float4 dv = *(const float4*)&attD[lane * 4];
    s = hv.x * sv.x + hv.y * sv.y + hv.z * sv.z + hv.w * sv.w;
    d = hv.x * dv.x + hv.y * dv.y + hv.z * dv.z + hv.w * dv.w;
  } else {
    float2 hv = *(const float2*)&h[(size_t)node * C + lane * 2];
    float2 sv = *(const float2*)&attS[lane * 2];
    float2 dv = *(const float2*)&attD[lane * 2];
    s = hv.x * sv.x + hv.y * sv.y;
    d = hv.x * dv.x + hv.y * dv.y;
  }
  for (int off = 32; off; off >>= 1) {
    s += __shfl_xor(s, off);
    d += __shfl_xor(d, off);
  }
  if (lane == 0) { aS[node] = s; aD[node] = d; }
}

// ---------------- layer-1 fused softmax + gather-aggregate ----------------
// One wave per dst node. Fast path (deg<=64): col+alpha live in lane
// registers, broadcast via shfl; gather loop is 8 independent 1KB row loads
// per group with zero scalar loads. Epilogue: +bias, ELU, 3-way bf16 split.
__global__ __launch_bounds__(256) void aggr_l1_fused(
    const int* __restrict__ rp, const int* __restrict__ col,
    const float* __restrict__ aS, const float* __restrict__ aD,
    const float* __restrict__ h, const float* __restrict__ bias,
    u16* __restrict__ embH, u16* __restrict__ embM, u16* __restrict__ embL,
    int n) {
  int node = (blockIdx.x * 256 + threadIdx.x) >> 6;
  int lane = threadIdx.x & 63;
  if (node >= n) return;
  int s0 = rp[node], s1 = rp[node + 1];
  int d = s1 - s0;
  float ad = aD[node];
  float4 acc = make_float4(0.f, 0.f, 0.f, 0.f);

  if (d <= 64) {
    // ---- alpha in registers (single coalesced gather pass) ----
    int c = 0;
    float e = -3.0e38f;
    if (lane < d) {
      c = clampi(col[s0 + lane], n);
      float t = aS[c] + ad;
      e = t >= 0.f ? t : 0.2f * t;
    }
    float m = e;
    for (int off = 32; off; off >>= 1) m = fmaxf(m, __shfl_xor(m, off));
    float ex = (lane < d) ? expf(e - m) : 0.f;
    float s = ex;
    for (int off = 32; off; off >>= 1) s += __shfl_xor(s, off);
    float al = ex * (1.f / (s + 1e-16f));   // 0 for lanes >= d
    // ---- gather: 8 rows in flight, shfl-broadcast col/alpha ----
    // j+t <= 63 always (j multiple of 8, j < d <= 64). Tail lanes have
    // c=0, al=0 -> harmless hot-row-0 loads.
    for (int j = 0; j < d; j += 8) {
#pragma unroll
      for (int t = 0; t < 8; ++t) {
        int ct = __shfl(c, j + t);
        float at = __shfl(al, j + t);
        float4 hv = *(const float4*)&h[(size_t)ct * HID + lane * 4];
        acc.x += at * hv.x; acc.y += at * hv.y;
        acc.z += at * hv.z; acc.w += at * hv.w;
      }
    }
  } else {
    // ---- fallback (rare): strided passes + serial gather ----
    float m = -3.0e38f;
    for (int i = s0 + lane; i < s1; i += 64) {
      float e = aS[clampi(col[i], n)] + ad;
      e = e >= 0.f ? e : 0.2f * e;
      m = fmaxf(m, e);
    }
    for (int off = 32; off; off >>= 1) m = fmaxf(m, __shfl_xor(m, off));
    float sum = 0.f;
    for (int i = s0 + lane; i < s1; i += 64) {
      float e = aS[clampi(col[i], n)] + ad;
      e = e >= 0.f ? e : 0.2f * e;
      sum += expf(e - m);
    }
    for (int off = 32; off; off >>= 1) sum += __shfl_xor(sum, off);
    float inv = 1.f / (sum + 1e-16f);
    for (int i = s0; i < s1; ++i) {
      int ci = clampi(col[i], n);
      float e = aS[ci] + ad;
      e = e >= 0.f ? e : 0.2f * e;
      float a = expf(e - m) * inv;
      float4 hv = *(const float4*)&h[(size_t)ci * HID + lane * 4];
      acc.x += a * hv.x; acc.y += a * hv.y; acc.z += a * hv.z; acc.w += a * hv.w;
    }
  }

  float4 bb = *(const float4*)&bias[lane * 4];
  float v0 = eluf(acc.x + bb.x);
  float v1 = eluf(acc.y + bb.y);
  float v2 = eluf(acc.z + bb.z);
  float v3 = eluf(acc.w + bb.w);
  ushort4 uh, um, ul;
  split3_bf16(v0, uh.x, um.x, ul.x);
  split3_bf16(v1, uh.y, um.y, ul.y);
  split3_bf16(v2, uh.z, um.z, ul.z);
  split3_bf16(v3, uh.w, um.w, ul.w);
  size_t o = (size_t)node * HID + lane * 4;
  *(ushort4*)&embH[o] = uh;
  *(ushort4*)&embM[o] = um;
  *(ushort4*)&embL[o] = ul;
}

// ---------------- layer-2 fused softmax + gather (C=128, fp32) -----------
__global__ __launch_bounds__(256) void aggr_l2_fused(
    const int* __restrict__ rp, const int* __restrict__ col,
    const float* __restrict__ aS, const float* __restrict__ aD,
    const float* __restrict__ h, const float* __restrict__ bias,
    float* __restrict__ out, int n) {
  int node = (blockIdx.x * 256 + threadIdx.x) >> 6;
  int lane = threadIdx.x & 63;
  if (node >= n) return;
  int s0 = rp[node], s1 = rp[node + 1];
  int d = s1 - s0;
  float ad = aD[node];
  float2 acc = make_float2(0.f, 0.f);

  if (d <= 64) {
    int c = 0;
    float e = -3.0e38f;
    if (lane < d) {
      c = clampi(col[s0 + lane], n);
      float t = aS[c] + ad;
      e = t >= 0.f ? t : 0.2f * t;
    }
    float m = e;
    for (int off = 32; off; off >>= 1) m = fmaxf(m, __shfl_xor(m, off));
    float ex = (lane < d) ? expf(e - m) : 0.f;
    float s = ex;
    for (int off = 32; off; off >>= 1) s += __shfl_xor(s, off);
    float al = ex * (1.f / (s + 1e-16f));
    for (int j = 0; j < d; j += 8) {
#pragma unroll
      for (int t = 0; t < 8; ++t) {
        int ct = __shfl(c, j + t);
        float at = __shfl(al, j + t);
        float2 hv = *(const float2*)&h[(size_t)ct * OUTF + lane * 2];
        acc.x += at * hv.x; acc.y += at * hv.y;
      }
    }
  } else {
    float m = -3.0e38f;
    for (int i = s0 + lane; i < s1; i += 64) {
      float e = aS[clampi(col[i], n)] + ad;
      e = e >= 0.f ? e : 0.2f * e;
      m = fmaxf(m, e);
    }
    for (int off = 32; off; off >>= 1) m = fmaxf(m, __shfl_xor(m, off));
    float sum = 0.f;
    for (int i = s0 + lane; i < s1; i += 64) {
      float e = aS[clampi(col[i], n)] + ad;
      e = e >= 0.f ? e : 0.2f * e;
      sum += expf(e - m);
    }
    for (int off = 32; off; off >>= 1) sum += __shfl_xor(sum, off);
    float inv = 1.f / (sum + 1e-16f);
    for (int i = s0; i < s1; ++i) {
      int ci = clampi(col[i], n);
      float e = aS[ci] + ad;
      e = e >= 0.f ? e : 0.2f * e;
      float a = expf(e - m) * inv;
      float2 hv = *(const float2*)&h[(size_t)ci * OUTF + lane * 2];
      acc.x += a * hv.x; acc.y += a * hv.y;
    }
  }

  float2 bb = *(const float2*)&bias[lane * 2];
  acc.x += bb.x; acc.y += bb.y;
  *(float2*)&out[(size_t)node * OUTF + lane * 2] = acc;
}

// ---------------- row softmax (+argmax for predictions) ----------------
__global__ __launch_bounds__(256) void softmax_rows(float* __restrict__ x,
                                                    float* __restrict__ pred,
                                                    int n) {
  int node = (blockIdx.x * 256 + threadIdx.x) >> 6;
  int lane = threadIdx.x & 63;
  if (node >= n) return;
  float2 v = *(float2*)&x[(size_t)node * OUTF + lane * 2];
  float bv;
  int bi;
  if (v.y > v.x) { bv = v.y; bi = 2 * lane + 1; }
  else           { bv = v.x; bi = 2 * lane; }
  for (int off = 32; off; off >>= 1) {
    float ov = __shfl_xor(bv, off);
    int oi = __shfl_xor(bi, off);
    if (ov > bv || (ov == bv && oi < bi)) { bv = ov; bi = oi; }
  }
  float e0 = expf(v.x - bv), e1 = expf(v.y - bv);
  float s = e0 + e1;
  for (int off = 32; off; off >>= 1) s += __shfl_xor(s, off);
  float2 r;
  r.x = e0 / s;
  r.y = e1 / s;
  *(float2*)&x[(size_t)node * OUTF + lane * 2] = r;
  if (pred != nullptr && lane == 0) pred[node] = (float)bi;
}

// ---------------- host orchestration ----------------
extern "C" void kernel_launch(void* const* d_in, const int* in_sizes, int n_in,
                              void* d_out, int out_size, void* d_ws, size_t ws_size,
                              hipStream_t stream) {
  const int N = N_NODES, E = E_EDGES;
  const float* x     = (const float*)d_in[0];
  const int*   ei1   = (const int*)d_in[1];
  const int*   ei2   = (const int*)d_in[2];
  const float* W1    = (const float*)d_in[3];
  const float* attS1 = (const float*)d_in[4];
  const float* attD1 = (const float*)d_in[5];
  const float* b1    = (const float*)d_in[6];
  const float* W2    = (const float*)d_in[7];
  const float* attS2 = (const float*)d_in[8];
  const float* attD2 = (const float*)d_in[9];
  const float* b2    = (const float*)d_in[10];
  const float* W3    = (const float*)d_in[11];
  const float* attS3 = (const float*)d_in[12];
  const float* attD3 = (const float*)d_in[13];
  const float* b3    = (const float*)d_in[14];

  char* ws = (char*)d_ws;
  size_t off = 0;
  auto take = [&](size_t bytes) {
    off = (off + 255) & ~(size_t)255;
    size_t o = off;
    off += bytes;
    return o;
  };
  int*   col1 = (int*)(ws + take((size_t)EP_EDGES * 4));
  int*   col2 = (int*)(ws + take((size_t)EP_EDGES * 4));
  int*   rp1  = (int*)(ws + take((size_t)(N + 1) * 4));
  int*   rp2  = (int*)(ws + take((size_t)(N + 1) * 4));
  int*   wp1  = (int*)(ws + take((size_t)N * 4));
  int*   wp2  = (int*)(ws + take((size_t)N * 4));
  int*   flag = (int*)(ws + take(256));
  float* h1h  = (float*)(ws + take((size_t)N * HID * 4));       // 51.2 MB
  u16*   embH = (u16*)(ws + take((size_t)N * HID * 2));         // 25.6 MB x3
  u16*   embM = (u16*)(ws + take((size_t)N * HID * 2));
  u16*   embL = (u16*)(ws + take((size_t)N * HID * 2));
  float* h2   = (float*)(ws + take((size_t)N * OUTF * 4 * 2));  // h2+h3
  float* h3   = h2 + (size_t)N * OUTF;
  u16*   W1Th = (u16*)(ws + take((size_t)IN_F * HID * HEADS * 2));  // [2048][512]
  u16*   W1Tm = (u16*)(ws + take((size_t)IN_F * HID * HEADS * 2));
  u16*   W1Tl = (u16*)(ws + take((size_t)IN_F * HID * HEADS * 2));
  u16*   W2Th = (u16*)(ws + take((size_t)HID * HEADS * OUTF * 2)); // [128][2048]
  u16*   W2Tm = (u16*)(ws + take((size_t)HID * HEADS * OUTF * 2));
  u16*   W2Tl = (u16*)(ws + take((size_t)HID * HEADS * OUTF * 2));
  u16*   W3Th = (u16*)(ws + take((size_t)HID * HEADS * OUTF * 2));
  u16*   W3Tm = (u16*)(ws + take((size_t)HID * HEADS * OUTF * 2));
  u16*   W3Tl = (u16*)(ws + take((size_t)HID * HEADS * OUTF * 2)); // dummy L
  float* as1  = (float*)(ws + take((size_t)N * 4));
  float* ad1  = (float*)(ws + take((size_t)N * 4));
  float* as2  = (float*)(ws + take((size_t)N * 4));
  float* ad2  = (float*)(ws + take((size_t)N * 4));
  float* as3  = (float*)(ws + take((size_t)N * 4));
  float* ad3  = (float*)(ws + take((size_t)N * 4));

  float* outp = (float*)d_out;
  float* x1   = outp;                         // logits   [N,128]
  float* x2   = outp + (size_t)N * OUTF;      // logits_2 [N,128]
  float* pred = outp + (size_t)2 * N * OUTF;  // predictions [N]

  const int gN = (N + 255) / 256;
  const int gE = (E + 255) / 256;
  const int gW = (N + 3) / 4;                 // one wave per node
  const int gM = (N + GBM - 1) / GBM;         // 391

  // ---- weight transpose + 3-way splits ----
  k_split3_t<<<(IN_F * HID * HEADS + 255) / 256, 256, 0, stream>>>(
      W1, W1Th, W1Tm, W1Tl, 9, 511, HID * HEADS, IN_F * HID * HEADS);
  k_split3_t<<<(HID * HEADS * OUTF + 255) / 256, 256, 0, stream>>>(
      W2, W2Th, W2Tm, W2Tl, 11, 2047, OUTF, HID * HEADS * OUTF);
  k_split3_t<<<(HID * HEADS * OUTF + 255) / 256, 256, 0, stream>>>(
      W3, W3Th, W3Tm, W3Tl, 11, 2047, OUTF, HID * HEADS * OUTF);

  // ---- edge dtype detection + CSR build (both graphs) ----
  k_detect<<<1, 256, 0, stream>>>(ei1, flag);

  k_init_deg<<<gN, 256, 0, stream>>>(wp1, N);
  k_count<<<gE, 256, 0, stream>>>(ei1, flag, wp1, E);
  k_scan<<<1, 1024, 0, stream>>>(wp1, rp1, N);
  k_fill_self<<<gN, 256, 0, stream>>>(rp1, wp1, col1, N);
  k_fill_edges<<<gE, 256, 0, stream>>>(ei1, flag, wp1, col1, E);

  k_init_deg<<<gN, 256, 0, stream>>>(wp2, N);
  k_count<<<gE, 256, 0, stream>>>(ei2, flag, wp2, E);
  k_scan<<<1, 1024, 0, stream>>>(wp2, rp2, N);
  k_fill_self<<<gN, 256, 0, stream>>>(rp2, wp2, col2, N);
  k_fill_edges<<<gE, 256, 0, stream>>>(ei2, flag, wp2, col2, E);

  // ---- zero layer-2 K-partial accumulators ----
  hipMemsetAsync(h2, 0, (size_t)N * OUTF * 4 * 2, stream);

  // ---- layer 1, one head at a time ----
  for (int h = 0; h < HEADS; ++h) {
    gemm1_k<<<dim3(gM, HID / GBN), 256, 0, stream>>>(
        x, IN_F,
        W1Th + (size_t)h * HID * IN_F, W1Tm + (size_t)h * HID * IN_F,
        W1Tl + (size_t)h * HID * IN_F, IN_F, h1h, HID, N, IN_F);
    att_dot<HID><<<gW, 256, 0, stream>>>(h1h, attS1 + (size_t)h * HID,
                                         attD1 + (size_t)h * HID, as1, ad1, N);
    aggr_l1_fused<<<gW, 256, 0, stream>>>(rp1, col1, as1, ad1, h1h,
                                          b1 + (size_t)h * HID,
                                          embH, embM, embL, N);
    gemm23_k<<<dim3(gM, 1, 2), 256, 0, stream>>>(
        embH, embM, embL, HID,
        W2Th + (size_t)h * HID, W2Tm + (size_t)h * HID, W2Tl + (size_t)h * HID,
        W3Th + (size_t)h * HID, W3Tm + (size_t)h * HID, HID * HEADS,
        h2, h3, OUTF, N, HID);
  }

  // ---- layer 2 attention + aggregation (heads=1) ----
  att_dot<OUTF><<<gW, 256, 0, stream>>>(h2, attS2, attD2, as2, ad2, N);
  att_dot<OUTF><<<gW, 256, 0, stream>>>(h3, attS3, attD3, as3, ad3, N);
  aggr_l2_fused<<<gW, 256, 0, stream>>>(rp1, col1, as2, ad2, h2, b2, x1, N);
  aggr_l2_fused<<<gW, 256, 0, stream>>>(rp2, col2, as3, ad3, h3, b3, x2, N);

  // ---- softmax rows (+argmax -> predictions) ----
  softmax_rows<<<gW, 256, 0, stream>>>(x1, pred, N);
  softmax_rows<<<gW, 256, 0, stream>>>(x2, nullptr, N);
}